// Round 1
// baseline (1001.537 us; speedup 1.0000x reference)
//
#include <hip/hip_runtime.h>

// GovernanceAwareAttention — round 0: correct fp32 baseline.
// B=2, S=1024, HID=1024, NH=16, CH=32, HD=64, TRUST=64
//
// Pipeline:
//  1. Q,K,V   = x @ {Wq,Wk,Wv} + b      [2048,1024]x[1024,1024]
//     CQ,CK   = x @ {Wcq,Wck} + b       [2048,1024]x[1024,2048]
//  2. tw      = trust @ Wt + bt          [2,64]x[64,16]
//  3. cmean   = (CQ @ CK^T) * scale/CH   (mean over const heads == full-dim dot / CH)
//  4. logits  = (Q_h @ K_h^T * scale + mask) * tw[b,h] + cmean   -> d_out probs region
//  5. softmax rows in-place (probs is an output)
//  6. ctx     = probs @ V_h
//  7. out     = ctx @ Wo + bo            -> d_out[0 : B*S*HID]

#define BM 64
#define BN 64
#define BK 16

static constexpr int Sq = 1024;
static constexpr int HIDc = 1024;
static constexpr int NHc = 16;
static constexpr int HDc = 64;
static constexpr int CHc = 32;

// ---------------- generic NN GEMM + bias: C[M,N] = A[M,K]@B[K,N] + bias ----------------
__global__ __launch_bounds__(256) void gemm_nn_bias(
    const float* __restrict__ A, const float* __restrict__ B,
    const float* __restrict__ bias, float* __restrict__ C,
    int M, int N, int K, int lda, int ldb, int ldc)
{
    __shared__ float As[BM][BK + 1];
    __shared__ float Bs[BK][BN];
    int tid = threadIdx.x;
    int tx = tid & 15, ty = tid >> 4;
    int bm = blockIdx.x * BM, bn = blockIdx.y * BN;
    float acc[4][4] = {};
    for (int k0 = 0; k0 < K; k0 += BK) {
#pragma unroll
        for (int i = 0; i < 4; i++) {
            int idx = tid + i * 256;
            int r = idx >> 4, c = idx & 15;       // BM x BK
            As[r][c] = A[(size_t)(bm + r) * lda + k0 + c];
        }
#pragma unroll
        for (int i = 0; i < 4; i++) {
            int idx = tid + i * 256;
            int r = idx >> 6, c = idx & 63;       // BK x BN
            Bs[r][c] = B[(size_t)(k0 + r) * ldb + bn + c];
        }
        __syncthreads();
#pragma unroll
        for (int kk = 0; kk < BK; kk++) {
            float a[4], b[4];
#pragma unroll
            for (int i = 0; i < 4; i++) a[i] = As[ty * 4 + i][kk];
#pragma unroll
            for (int j = 0; j < 4; j++) b[j] = Bs[kk][tx * 4 + j];
#pragma unroll
            for (int i = 0; i < 4; i++)
#pragma unroll
                for (int j = 0; j < 4; j++) acc[i][j] += a[i] * b[j];
        }
        __syncthreads();
    }
#pragma unroll
    for (int i = 0; i < 4; i++)
#pragma unroll
        for (int j = 0; j < 4; j++) {
            int r = bm + ty * 4 + i, c = bn + tx * 4 + j;
            float v = acc[i][j] + (bias ? bias[c] : 0.0f);
            C[(size_t)r * ldc + c] = v;
        }
}

// ---------------- trust weights: tw[b,h] = trust[b,:] @ Wt[:,h] + bt[h] ----------------
__global__ void tw_kernel(const float* __restrict__ trust, const float* __restrict__ Wt,
                          const float* __restrict__ bt, float* __restrict__ tw)
{
    int i = threadIdx.x;          // 0..31 = b*16+h
    if (i >= 2 * NHc) return;
    int b = i >> 4, h = i & 15;
    float s = bt[h];
    for (int k = 0; k < 64; k++) s += trust[b * 64 + k] * Wt[k * NHc + h];
    tw[i] = s;
}

// ---------------- cmean[b,q,k] = alpha * dot(CQ[b,q,:], CK[b,k,:])  (K=2048) ----------------
__global__ __launch_bounds__(256) void cmean_kernel(
    const float* __restrict__ CQ, const float* __restrict__ CK, float* __restrict__ CM)
{
    const int Kd = 2048;
    const float alpha = 0.125f / 32.0f;   // (1/sqrt(64)) / CH
    int b = blockIdx.z;
    const float* A = CQ + (size_t)b * Sq * Kd;
    const float* Bm = CK + (size_t)b * Sq * Kd;
    float* C = CM + (size_t)b * Sq * Sq;

    __shared__ float As[BM][BK + 1];
    __shared__ float Bs[BN][BK + 1];
    int tid = threadIdx.x;
    int tx = tid & 15, ty = tid >> 4;
    int bm = blockIdx.x * BM, bn = blockIdx.y * BN;
    float acc[4][4] = {};
    for (int k0 = 0; k0 < Kd; k0 += BK) {
#pragma unroll
        for (int i = 0; i < 4; i++) {
            int idx = tid + i * 256;
            int r = idx >> 4, c = idx & 15;
            As[r][c] = A[(size_t)(bm + r) * Kd + k0 + c];
            Bs[r][c] = Bm[(size_t)(bn + r) * Kd + k0 + c];
        }
        __syncthreads();
#pragma unroll
        for (int kk = 0; kk < BK; kk++) {
            float a[4], bb[4];
#pragma unroll
            for (int i = 0; i < 4; i++) a[i] = As[ty * 4 + i][kk];
#pragma unroll
            for (int j = 0; j < 4; j++) bb[j] = Bs[tx * 4 + j][kk];
#pragma unroll
            for (int i = 0; i < 4; i++)
#pragma unroll
                for (int j = 0; j < 4; j++) acc[i][j] += a[i] * bb[j];
        }
        __syncthreads();
    }
#pragma unroll
    for (int i = 0; i < 4; i++)
#pragma unroll
        for (int j = 0; j < 4; j++) {
            int r = bm + ty * 4 + i, c = bn + tx * 4 + j;
            C[(size_t)r * Sq + c] = acc[i][j] * alpha;
        }
}

// ---------------- logits[b,h,q,k] = (Q_h@K_h^T*scale + mask)*tw + cmean ----------------
__global__ __launch_bounds__(256) void scores_kernel(
    const float* __restrict__ Q, const float* __restrict__ Kbuf,
    const float* __restrict__ mask, const float* __restrict__ tw,
    const float* __restrict__ CM, float* __restrict__ logits)
{
    const int Kd = HDc;           // 64
    int z = blockIdx.z;           // b*NH+h
    int b = z >> 4, h = z & 15;
    const float* A = Q + (size_t)b * Sq * HIDc + h * HDc;    // [S,64] lda=1024
    const float* Bm = Kbuf + (size_t)b * Sq * HIDc + h * HDc;
    const float* Mrow = mask + (size_t)b * Sq * Sq;
    const float* CMb = CM + (size_t)b * Sq * Sq;
    float* L = logits + (size_t)z * Sq * Sq;
    float twv = tw[z];

    __shared__ float As[BM][BK + 1];
    __shared__ float Bs[BN][BK + 1];
    int tid = threadIdx.x;
    int tx = tid & 15, ty = tid >> 4;
    int bm = blockIdx.x * BM, bn = blockIdx.y * BN;
    float acc[4][4] = {};
    for (int k0 = 0; k0 < Kd; k0 += BK) {
#pragma unroll
        for (int i = 0; i < 4; i++) {
            int idx = tid + i * 256;
            int r = idx >> 4, c = idx & 15;
            As[r][c] = A[(size_t)(bm + r) * HIDc + k0 + c];
            Bs[r][c] = Bm[(size_t)(bn + r) * HIDc + k0 + c];
        }
        __syncthreads();
#pragma unroll
        for (int kk = 0; kk < BK; kk++) {
            float a[4], bb[4];
#pragma unroll
            for (int i = 0; i < 4; i++) a[i] = As[ty * 4 + i][kk];
#pragma unroll
            for (int j = 0; j < 4; j++) bb[j] = Bs[tx * 4 + j][kk];
#pragma unroll
            for (int i = 0; i < 4; i++)
#pragma unroll
                for (int j = 0; j < 4; j++) acc[i][j] += a[i] * bb[j];
        }
        __syncthreads();
    }
#pragma unroll
    for (int i = 0; i < 4; i++)
#pragma unroll
        for (int j = 0; j < 4; j++) {
            int q = bm + ty * 4 + i, k = bn + tx * 4 + j;
            float v = (acc[i][j] * 0.125f + Mrow[(size_t)q * Sq + k]) * twv
                      + CMb[(size_t)q * Sq + k];
            L[(size_t)q * Sq + k] = v;
        }
}

// ---------------- row softmax in-place over last dim (1024) ----------------
__global__ __launch_bounds__(256) void softmax_rows(float* __restrict__ logits)
{
    size_t row = blockIdx.x;
    float* p = logits + row * Sq;
    int t = threadIdx.x;
    float v[4];
    float m = -1e30f;
#pragma unroll
    for (int i = 0; i < 4; i++) { v[i] = p[t + 256 * i]; m = fmaxf(m, v[i]); }
#pragma unroll
    for (int off = 32; off; off >>= 1) m = fmaxf(m, __shfl_xor(m, off));
    __shared__ float red[4];
    int wid = t >> 6;
    if ((t & 63) == 0) red[wid] = m;
    __syncthreads();
    m = fmaxf(fmaxf(red[0], red[1]), fmaxf(red[2], red[3]));
    __syncthreads();
    float s = 0.0f;
#pragma unroll
    for (int i = 0; i < 4; i++) { v[i] = __expf(v[i] - m); s += v[i]; }
#pragma unroll
    for (int off = 32; off; off >>= 1) s += __shfl_xor(s, off);
    if ((t & 63) == 0) red[wid] = s;
    __syncthreads();
    s = red[0] + red[1] + red[2] + red[3];
    float inv = 1.0f / s;
#pragma unroll
    for (int i = 0; i < 4; i++) p[t + 256 * i] = v[i] * inv;
}

// ---------------- ctx[b,q,h*64+d] = sum_k probs[b,h,q,k] * V[b,k,h*64+d] ----------------
__global__ __launch_bounds__(256) void ctx_kernel(
    const float* __restrict__ P, const float* __restrict__ V, float* __restrict__ CTX)
{
    int z = blockIdx.z;           // b*NH+h
    int b = z >> 4, h = z & 15;
    const float* A = P + (size_t)z * Sq * Sq;                 // [S,S]
    const float* Bm = V + (size_t)b * Sq * HIDc + h * HDc;    // [S,64] ldb=1024
    float* C = CTX + (size_t)b * Sq * HIDc + h * HDc;

    __shared__ float As[BM][BK + 1];
    __shared__ float Bs[BK][BN];
    int tid = threadIdx.x;
    int tx = tid & 15, ty = tid >> 4;
    int bm = blockIdx.x * BM;     // bn = 0 (BN == 64 == HD)
    float acc[4][4] = {};
    for (int k0 = 0; k0 < Sq; k0 += BK) {
#pragma unroll
        for (int i = 0; i < 4; i++) {
            int idx = tid + i * 256;
            int r = idx >> 4, c = idx & 15;
            As[r][c] = A[(size_t)(bm + r) * Sq + k0 + c];
        }
#pragma unroll
        for (int i = 0; i < 4; i++) {
            int idx = tid + i * 256;
            int r = idx >> 6, c = idx & 63;
            Bs[r][c] = Bm[(size_t)(k0 + r) * HIDc + c];
        }
        __syncthreads();
#pragma unroll
        for (int kk = 0; kk < BK; kk++) {
            float a[4], bb[4];
#pragma unroll
            for (int i = 0; i < 4; i++) a[i] = As[ty * 4 + i][kk];
#pragma unroll
            for (int j = 0; j < 4; j++) bb[j] = Bs[kk][tx * 4 + j];
#pragma unroll
            for (int i = 0; i < 4; i++)
#pragma unroll
                for (int j = 0; j < 4; j++) acc[i][j] += a[i] * bb[j];
        }
        __syncthreads();
    }
#pragma unroll
    for (int i = 0; i < 4; i++)
#pragma unroll
        for (int j = 0; j < 4; j++) {
            int r = bm + ty * 4 + i, c = tx * 4 + j;
            C[(size_t)r * HIDc + c] = acc[i][j];
        }
}

extern "C" void kernel_launch(void* const* d_in, const int* in_sizes, int n_in,
                              void* d_out, int out_size, void* d_ws, size_t ws_size,
                              hipStream_t stream)
{
    (void)in_sizes; (void)n_in; (void)out_size; (void)ws_size;
    const float* x     = (const float*)d_in[0];
    const float* mask  = (const float*)d_in[1];
    const float* trust = (const float*)d_in[2];
    const float* Wq  = (const float*)d_in[3];  const float* bq  = (const float*)d_in[4];
    const float* Wk  = (const float*)d_in[5];  const float* bk  = (const float*)d_in[6];
    const float* Wv  = (const float*)d_in[7];  const float* bv  = (const float*)d_in[8];
    const float* Wcq = (const float*)d_in[9];  const float* bcq = (const float*)d_in[10];
    const float* Wck = (const float*)d_in[11]; const float* bck = (const float*)d_in[12];
    // d_in[13]=Wcv, d_in[14]=bcv are unused by the reference (cv is never computed)
    const float* Wt  = (const float*)d_in[15]; const float* bt  = (const float*)d_in[16];
    const float* Wo  = (const float*)d_in[17]; const float* bo  = (const float*)d_in[18];

    float* out = (float*)d_out;                       // [B,S,HID] = 2,097,152 floats
    float* probs = out + (size_t)2 * Sq * HIDc;       // [B,NH,S,S] = 33,554,432 floats

    float* ws = (float*)d_ws;
    float* Qb  = ws;                          // 2,097,152
    float* Kb  = Qb  + (size_t)2097152;
    float* Vb  = Kb  + (size_t)2097152;
    float* CQ  = Vb  + (size_t)2097152;       // 4,194,304
    float* CK  = CQ  + (size_t)4194304;
    float* CM  = CK  + (size_t)4194304;       // 2,097,152
    float* CTX = CM  + (size_t)2097152;       // 2,097,152
    float* TW  = CTX + (size_t)2097152;       // 32

    const int M = 2 * Sq;  // 2048

    // 1. projections
    dim3 blk(256);
    gemm_nn_bias<<<dim3(M / BM, HIDc / BN, 1), blk, 0, stream>>>(x, Wq, bq, Qb, M, HIDc, HIDc, HIDc, HIDc, HIDc);
    gemm_nn_bias<<<dim3(M / BM, HIDc / BN, 1), blk, 0, stream>>>(x, Wk, bk, Kb, M, HIDc, HIDc, HIDc, HIDc, HIDc);
    gemm_nn_bias<<<dim3(M / BM, HIDc / BN, 1), blk, 0, stream>>>(x, Wv, bv, Vb, M, HIDc, HIDc, HIDc, HIDc, HIDc);
    gemm_nn_bias<<<dim3(M / BM, 2048 / BN, 1), blk, 0, stream>>>(x, Wcq, bcq, CQ, M, 2048, HIDc, HIDc, 2048, 2048);
    gemm_nn_bias<<<dim3(M / BM, 2048 / BN, 1), blk, 0, stream>>>(x, Wck, bck, CK, M, 2048, HIDc, HIDc, 2048, 2048);

    // 2. trust weights
    tw_kernel<<<1, 64, 0, stream>>>(trust, Wt, bt, TW);

    // 3. constitutional mean
    cmean_kernel<<<dim3(Sq / BM, Sq / BN, 2), blk, 0, stream>>>(CQ, CK, CM);

    // 4. logits into probs buffer
    scores_kernel<<<dim3(Sq / BM, Sq / BN, 2 * NHc), blk, 0, stream>>>(Qb, Kb, mask, TW, CM, probs);

    // 5. softmax in place
    softmax_rows<<<dim3(2 * NHc * Sq), blk, 0, stream>>>(probs);

    // 6. context
    ctx_kernel<<<dim3(Sq / BM, 1, 2 * NHc), blk, 0, stream>>>(probs, Vb, CTX);

    // 7. output projection
    gemm_nn_bias<<<dim3(M / BM, HIDc / BN, 1), blk, 0, stream>>>(CTX, Wo, bo, out, M, HIDc, HIDc, HIDc, HIDc, HIDc);
}

// Round 2
// 330.808 us; speedup vs baseline: 3.0275x; 3.0275x over previous
//
#include <hip/hip_runtime.h>

// GovernanceAwareAttention — round 1: bf16 MFMA everywhere.
// B=2, S=1024, HID=1024, NH=16, CH=32, HD=64
//
// All GEMMs in NT form: A[M,K] bf16 row-major, Bt[N,K] bf16 row-major,
// mfma_f32_16x16x32_bf16, fp32 accumulate, fused epilogues.
//  prep: x->bf16; W{q,k,v,o,cq,ck} -> bf16 transposed [N][K]; V -> Vt[b][d][s]
//  1. Q,K,V,CQ,CK projections (bf16 out)
//  2. tw  (tiny fp32)
//  3. cmean = CQ@CK^T * 0.125/32        (fp32 out)
//  4. logits = (Q_h@K_h^T*0.125 + mask)*tw + cmean  -> probs region (fp32)
//  5. softmax rows in place (fp32)
//  6. ctx = probs@V  (probs fp32 -> bf16 staged on the fly, Vt as B)
//  7. out = ctx@Wo^T + bo (fp32)

typedef __bf16 bf16x8 __attribute__((ext_vector_type(8)));
typedef float  f32x4  __attribute__((ext_vector_type(4)));

static constexpr int Sq = 1024;

// ---------- staging: global -> LDS, 16B per lane, linear layout ----------
template<int ROWS>
__device__ __forceinline__ void stage_g(const __bf16* g, int ld, __bf16* s, int tid)
{
    constexpr int PER = (ROWS * 4) / 256;        // 16B chunks per thread (BK=32)
    int w = tid >> 6, l = tid & 63;
#pragma unroll
    for (int i = 0; i < PER; i++) {
        int bc = w * 64 + i * 256;               // wave-uniform chunk base
        int chunk = bc + l;
        int row = chunk >> 2, part = (chunk & 3) * 8;
        const __bf16* gp = g + (size_t)row * ld + part;
        __bf16* sp = s + (size_t)bc * 8;         // wave-uniform LDS base
        __builtin_amdgcn_global_load_lds(
            (__attribute__((address_space(1))) void*)(gp),
            (__attribute__((address_space(3))) void*)(sp), 16, 0, 0);
    }
}

// fp32 global -> bf16 LDS (for probs as A operand), 128x32 tile
__device__ __forceinline__ void stage_f32(const float* g, int ld, __bf16* s, int tid)
{
    int row = tid >> 1, off = (tid & 1) * 16;
    const float* gp = g + (size_t)row * ld + off;
    bf16x8 o0, o1;
#pragma unroll
    for (int u = 0; u < 8; u++) o0[u] = (__bf16)gp[u];
#pragma unroll
    for (int u = 0; u < 8; u++) o1[u] = (__bf16)gp[8 + u];
    *(bf16x8*)(s + (size_t)row * 32 + off)     = o0;
    *(bf16x8*)(s + (size_t)row * 32 + off + 8) = o1;
}

// ---------- unified NT MFMA GEMM ----------
// EPI: 0 proj (bf16 + bias), 1 outproj (f32 + bias), 2 cmean (f32 * alpha),
//      3 scores ((v*0.125+mask)*tw+cmean -> f32), 4 ctx (probs(f32)@Vt -> bf16)
template<int BM, int BN, int EPI>
__global__ __launch_bounds__(256) void gemm_nt(
    const __bf16* __restrict__ A, const float* __restrict__ Af, int lda,
    const __bf16* __restrict__ B, int ldb,
    void* __restrict__ Cout, int ldc,
    const float* __restrict__ bias, const float* __restrict__ mask,
    const float* __restrict__ CMp, const float* __restrict__ TWp,
    int Ksz, float alpha)
{
    constexpr int WM = BM / 2, WN = BN / 2, FM = WM / 16, FN = WN / 16;
    __shared__ __bf16 As[BM][32];
    __shared__ __bf16 Bs[BN][32];
    int tid = threadIdx.x;
    int w = tid >> 6, l = tid & 63;
    int wr = w >> 1, wc = w & 1;
    int lr = l & 15, kp = (l >> 4) * 8;
    int bm = blockIdx.x * BM, bn = blockIdx.y * BN;
    int z = blockIdx.z;

    size_t zA = 0, zB = 0, zC = 0, zM = 0;
    float twv = 0.f;
    if constexpr (EPI == 2) {
        zA = (size_t)z * Sq * 2048; zB = zA; zC = (size_t)z * Sq * Sq;
    } else if constexpr (EPI == 3) {
        int b = z >> 4, h = z & 15;
        zA = (size_t)b * Sq * 1024 + h * 64; zB = zA;
        zC = (size_t)z * Sq * Sq; zM = (size_t)b * Sq * Sq;
        twv = TWp[z];
    } else if constexpr (EPI == 4) {
        int b = z >> 4, h = z & 15;
        zA = (size_t)z * Sq * Sq;
        zB = (size_t)b * 1024 * 1024 + (size_t)h * 64 * 1024;
        zC = (size_t)b * Sq * 1024 + h * 64;
    }

    f32x4 acc[FM][FN];
#pragma unroll
    for (int i = 0; i < FM; i++)
#pragma unroll
        for (int j = 0; j < FN; j++) acc[i][j] = (f32x4){0.f, 0.f, 0.f, 0.f};

    for (int k0 = 0; k0 < Ksz; k0 += 32) {
        if constexpr (EPI == 4)
            stage_f32(Af + zA + (size_t)bm * lda + k0, lda, &As[0][0], tid);
        else
            stage_g<BM>(A + zA + (size_t)bm * lda + k0, lda, &As[0][0], tid);
        stage_g<BN>(B + zB + (size_t)bn * ldb + k0, ldb, &Bs[0][0], tid);
        __syncthreads();
        bf16x8 av[FM], bv[FN];
#pragma unroll
        for (int i = 0; i < FM; i++) av[i] = *(const bf16x8*)&As[wr * WM + i * 16 + lr][kp];
#pragma unroll
        for (int j = 0; j < FN; j++) bv[j] = *(const bf16x8*)&Bs[wc * WN + j * 16 + lr][kp];
#pragma unroll
        for (int i = 0; i < FM; i++)
#pragma unroll
            for (int j = 0; j < FN; j++)
                acc[i][j] = __builtin_amdgcn_mfma_f32_16x16x32_bf16(av[i], bv[j], acc[i][j], 0, 0, 0);
        __syncthreads();
    }

    int dr = (l >> 4) * 4, dc = l & 15;
#pragma unroll
    for (int i = 0; i < FM; i++) {
#pragma unroll
        for (int j = 0; j < FN; j++) {
#pragma unroll
            for (int t = 0; t < 4; t++) {
                int row = bm + wr * WM + i * 16 + dr + t;
                int col = bn + wc * WN + j * 16 + dc;
                float v = acc[i][j][t];
                size_t off = zC + (size_t)row * ldc + col;
                if constexpr (EPI == 0) {
                    ((__bf16*)Cout)[off] = (__bf16)(v + bias[col]);
                } else if constexpr (EPI == 1) {
                    ((float*)Cout)[off] = v + bias[col];
                } else if constexpr (EPI == 2) {
                    ((float*)Cout)[off] = v * alpha;
                } else if constexpr (EPI == 3) {
                    size_t mo = zM + (size_t)row * Sq + col;
                    ((float*)Cout)[off] = (v * 0.125f + mask[mo]) * twv + CMp[mo];
                } else {
                    ((__bf16*)Cout)[off] = (__bf16)v;
                }
            }
        }
    }
}

// ---------- prep kernels ----------
__global__ __launch_bounds__(256) void convert_f32_bf16(
    const float* __restrict__ src, __bf16* __restrict__ dst)
{
    int i = blockIdx.x * 256 + threadIdx.x;
    size_t base = (size_t)i * 8;
    float4 a = *(const float4*)(src + base);
    float4 b = *(const float4*)(src + base + 4);
    bf16x8 o;
    o[0] = (__bf16)a.x; o[1] = (__bf16)a.y; o[2] = (__bf16)a.z; o[3] = (__bf16)a.w;
    o[4] = (__bf16)b.x; o[5] = (__bf16)b.y; o[6] = (__bf16)b.z; o[7] = (__bf16)b.w;
    *(bf16x8*)(dst + base) = o;
}

// src[K][N] f32 -> dst[N][K] bf16
__global__ __launch_bounds__(256) void transpose_f32_bf16(
    const float* __restrict__ src, __bf16* __restrict__ dst, int K, int N)
{
    __shared__ float t[32][33];
    int tx = threadIdx.x, ty = threadIdx.y;
    int n0 = blockIdx.x * 32, k0 = blockIdx.y * 32;
#pragma unroll
    for (int i = 0; i < 4; i++)
        t[ty + i * 8][tx] = src[(size_t)(k0 + ty + i * 8) * N + n0 + tx];
    __syncthreads();
#pragma unroll
    for (int i = 0; i < 4; i++)
        dst[(size_t)(n0 + ty + i * 8) * K + k0 + tx] = (__bf16)t[tx][ty + i * 8];
}

// batched bf16 transpose: src[z][K][N] -> dst[z][N][K]
__global__ __launch_bounds__(256) void transpose_bf16(
    const __bf16* __restrict__ src, __bf16* __restrict__ dst, int K, int N)
{
    int z = blockIdx.z;
    src += (size_t)z * K * N; dst += (size_t)z * K * N;
    __shared__ __bf16 t[32][33];
    int tx = threadIdx.x, ty = threadIdx.y;
    int n0 = blockIdx.x * 32, k0 = blockIdx.y * 32;
#pragma unroll
    for (int i = 0; i < 4; i++)
        t[ty + i * 8][tx] = src[(size_t)(k0 + ty + i * 8) * N + n0 + tx];
    __syncthreads();
#pragma unroll
    for (int i = 0; i < 4; i++)
        dst[(size_t)(n0 + ty + i * 8) * K + k0 + tx] = t[tx][ty + i * 8];
}

__global__ void tw_kernel(const float* __restrict__ trust, const float* __restrict__ Wt,
                          const float* __restrict__ bt, float* __restrict__ tw)
{
    int i = threadIdx.x;
    if (i >= 32) return;
    int b = i >> 4, h = i & 15;
    float s = bt[h];
    for (int k = 0; k < 64; k++) s += trust[b * 64 + k] * Wt[k * 16 + h];
    tw[i] = s;
}

__global__ __launch_bounds__(256) void softmax_rows(float* __restrict__ logits)
{
    size_t row = blockIdx.x;
    float* p = logits + row * Sq;
    int t = threadIdx.x;
    float v[4];
    float m = -1e30f;
#pragma unroll
    for (int i = 0; i < 4; i++) { v[i] = p[t + 256 * i]; m = fmaxf(m, v[i]); }
#pragma unroll
    for (int off = 32; off; off >>= 1) m = fmaxf(m, __shfl_xor(m, off));
    __shared__ float red[4];
    int wid = t >> 6;
    if ((t & 63) == 0) red[wid] = m;
    __syncthreads();
    m = fmaxf(fmaxf(red[0], red[1]), fmaxf(red[2], red[3]));
    __syncthreads();
    float s = 0.0f;
#pragma unroll
    for (int i = 0; i < 4; i++) { v[i] = __expf(v[i] - m); s += v[i]; }
#pragma unroll
    for (int off = 32; off; off >>= 1) s += __shfl_xor(s, off);
    if ((t & 63) == 0) red[wid] = s;
    __syncthreads();
    s = red[0] + red[1] + red[2] + red[3];
    float inv = 1.0f / s;
#pragma unroll
    for (int i = 0; i < 4; i++) p[t + 256 * i] = v[i] * inv;
}

extern "C" void kernel_launch(void* const* d_in, const int* in_sizes, int n_in,
                              void* d_out, int out_size, void* d_ws, size_t ws_size,
                              hipStream_t stream)
{
    (void)in_sizes; (void)n_in; (void)out_size; (void)ws_size;
    const float* x     = (const float*)d_in[0];
    const float* mask  = (const float*)d_in[1];
    const float* trust = (const float*)d_in[2];
    const float* Wq  = (const float*)d_in[3];  const float* bq  = (const float*)d_in[4];
    const float* Wk  = (const float*)d_in[5];  const float* bk  = (const float*)d_in[6];
    const float* Wv  = (const float*)d_in[7];  const float* bv  = (const float*)d_in[8];
    const float* Wcq = (const float*)d_in[9];  const float* bcq = (const float*)d_in[10];
    const float* Wck = (const float*)d_in[11]; const float* bck = (const float*)d_in[12];
    const float* Wt  = (const float*)d_in[15]; const float* bt  = (const float*)d_in[16];
    const float* Wo  = (const float*)d_in[17]; const float* bo  = (const float*)d_in[18];

    float* out   = (float*)d_out;                 // [2,1024,1024] f32
    float* probs = out + (size_t)2 * Sq * 1024;   // [2,16,1024,1024] f32

    constexpr size_t MB = 1u << 20;
    char* w8 = (char*)d_ws;
    __bf16* xb   = (__bf16*)(w8 + 0 * MB);
    __bf16* WqT  = (__bf16*)(w8 + 4 * MB);
    __bf16* WkT  = (__bf16*)(w8 + 6 * MB);
    __bf16* WvT  = (__bf16*)(w8 + 8 * MB);
    __bf16* WoT  = (__bf16*)(w8 + 10 * MB);
    __bf16* WcqT = (__bf16*)(w8 + 12 * MB);
    __bf16* WckT = (__bf16*)(w8 + 16 * MB);
    __bf16* Qb   = (__bf16*)(w8 + 20 * MB);
    __bf16* Kb   = (__bf16*)(w8 + 24 * MB);
    __bf16* Vb   = (__bf16*)(w8 + 28 * MB);
    __bf16* Vt   = (__bf16*)(w8 + 32 * MB);
    __bf16* CQb  = (__bf16*)(w8 + 36 * MB);
    __bf16* CKb  = (__bf16*)(w8 + 44 * MB);
    float*  CM   = (float*) (w8 + 52 * MB);
    __bf16* CTXb = (__bf16*)(w8 + 60 * MB);
    float*  TW   = (float*) (w8 + 64 * MB);

    dim3 tb(32, 8);

    // prep
    convert_f32_bf16<<<1024, 256, 0, stream>>>(x, xb);
    transpose_f32_bf16<<<dim3(32, 32), tb, 0, stream>>>(Wq,  WqT,  1024, 1024);
    transpose_f32_bf16<<<dim3(32, 32), tb, 0, stream>>>(Wk,  WkT,  1024, 1024);
    transpose_f32_bf16<<<dim3(32, 32), tb, 0, stream>>>(Wv,  WvT,  1024, 1024);
    transpose_f32_bf16<<<dim3(32, 32), tb, 0, stream>>>(Wo,  WoT,  1024, 1024);
    transpose_f32_bf16<<<dim3(64, 32), tb, 0, stream>>>(Wcq, WcqT, 1024, 2048);
    transpose_f32_bf16<<<dim3(64, 32), tb, 0, stream>>>(Wck, WckT, 1024, 2048);
    tw_kernel<<<1, 64, 0, stream>>>(trust, Wt, bt, TW);

    // projections
    gemm_nt<128, 128, 0><<<dim3(16, 8, 1), 256, 0, stream>>>(
        xb, nullptr, 1024, WqT, 1024, Qb, 1024, bq, nullptr, nullptr, nullptr, 1024, 0.f);
    gemm_nt<128, 128, 0><<<dim3(16, 8, 1), 256, 0, stream>>>(
        xb, nullptr, 1024, WkT, 1024, Kb, 1024, bk, nullptr, nullptr, nullptr, 1024, 0.f);
    gemm_nt<128, 128, 0><<<dim3(16, 8, 1), 256, 0, stream>>>(
        xb, nullptr, 1024, WvT, 1024, Vb, 1024, bv, nullptr, nullptr, nullptr, 1024, 0.f);
    gemm_nt<128, 128, 0><<<dim3(16, 16, 1), 256, 0, stream>>>(
        xb, nullptr, 1024, WcqT, 1024, CQb, 2048, bcq, nullptr, nullptr, nullptr, 1024, 0.f);
    gemm_nt<128, 128, 0><<<dim3(16, 16, 1), 256, 0, stream>>>(
        xb, nullptr, 1024, WckT, 1024, CKb, 2048, bck, nullptr, nullptr, nullptr, 1024, 0.f);

    // V transpose for ctx B-operand: Vt[b][d][s]
    transpose_bf16<<<dim3(32, 32, 2), tb, 0, stream>>>(Vb, Vt, 1024, 1024);

    // cmean (alpha = 0.125/32)
    gemm_nt<128, 128, 2><<<dim3(8, 8, 2), 256, 0, stream>>>(
        CQb, nullptr, 2048, CKb, 2048, CM, 1024, nullptr, nullptr, nullptr, nullptr,
        2048, 0.00390625f);

    // scores -> logits in probs region
    gemm_nt<128, 128, 3><<<dim3(8, 8, 32), 256, 0, stream>>>(
        Qb, nullptr, 1024, Kb, 1024, probs, 1024, nullptr, mask, CM, TW, 64, 0.f);

    // softmax in place
    softmax_rows<<<dim3(32 * 1024), 256, 0, stream>>>(probs);

    // ctx = probs @ V  (A = fp32 probs staged to bf16, B = Vt)
    gemm_nt<128, 64, 4><<<dim3(8, 1, 32), 256, 0, stream>>>(
        nullptr, probs, 1024, Vt, 1024, CTXb, 1024, nullptr, nullptr, nullptr, nullptr,
        1024, 0.f);

    // output projection
    gemm_nt<128, 128, 1><<<dim3(16, 8, 1), 256, 0, stream>>>(
        CTXb, nullptr, 1024, WoT, 1024, out, 1024, bo, nullptr, nullptr, nullptr, 1024, 0.f);
}

// Round 3
// 230.887 us; speedup vs baseline: 4.3378x; 1.4328x over previous
//
#include <hip/hip_runtime.h>

// GovernanceAwareAttention — round 2: packed projections + fully fused
// scores->softmax->PV attention kernel (probs materialized once).
// B=2, S=1024, HID=1024, NH=16, CH=32, HD=64

typedef __bf16 bf16x8 __attribute__((ext_vector_type(8)));
typedef float  f32x4  __attribute__((ext_vector_type(4)));

static constexpr int Sq  = 1024;
static constexpr int LDP = 7168;      // packed projection row stride (3*1024 + 2*2048)

// ---------- staging: global -> LDS, 16B/lane, linear [ROWS][32] bf16 ----------
template<int ROWS>
__device__ __forceinline__ void stage_g(const __bf16* g, int ld, __bf16* s, int tid)
{
    constexpr int PER = (ROWS * 4) / 256;
    int w = tid >> 6, l = tid & 63;
#pragma unroll
    for (int i = 0; i < PER; i++) {
        int bc = w * 64 + i * 256;
        int chunk = bc + l;
        int row = chunk >> 2, part = (chunk & 3) * 8;
        const __bf16* gp = g + (size_t)row * ld + part;
        __bf16* sp = s + (size_t)bc * 8;
        __builtin_amdgcn_global_load_lds(
            (__attribute__((address_space(1))) void*)(gp),
            (__attribute__((address_space(3))) void*)(sp), 16, 0, 0);
    }
}

// ---------- NT MFMA GEMM.  EPI: 0 = bf16 out + bias, 1 = f32 out + bias, 2 = f32 * alpha (batched z) ----------
template<int BM, int BN, int EPI>
__global__ __launch_bounds__(256) void gemm_nt(
    const __bf16* __restrict__ A, int lda,
    const __bf16* __restrict__ B, int ldb,
    void* __restrict__ Cout, int ldc,
    const float* __restrict__ bias, int Ksz, float alpha)
{
    constexpr int WM = BM / 2, WN = BN / 2, FM = WM / 16, FN = WN / 16;
    __shared__ __bf16 As[BM][32];
    __shared__ __bf16 Bs[BN][32];
    int tid = threadIdx.x;
    int w = tid >> 6, l = tid & 63;
    int wr = w >> 1, wc = w & 1;
    int lr = l & 15, kp = (l >> 4) * 8;
    int bm = blockIdx.x * BM, bn = blockIdx.y * BN;
    int z = blockIdx.z;

    size_t zA = 0, zC = 0;
    if constexpr (EPI == 2) { zA = (size_t)z * 1024 * LDP; zC = (size_t)z * Sq * Sq; }

    f32x4 acc[FM][FN];
#pragma unroll
    for (int i = 0; i < FM; i++)
#pragma unroll
        for (int j = 0; j < FN; j++) acc[i][j] = (f32x4){0.f, 0.f, 0.f, 0.f};

    for (int k0 = 0; k0 < Ksz; k0 += 32) {
        stage_g<BM>(A + zA + (size_t)bm * lda + k0, lda, &As[0][0], tid);
        stage_g<BN>(B + zA + (size_t)bn * ldb + k0, ldb, &Bs[0][0], tid);
        __syncthreads();
        bf16x8 av[FM], bv[FN];
#pragma unroll
        for (int i = 0; i < FM; i++) av[i] = *(const bf16x8*)&As[wr * WM + i * 16 + lr][kp];
#pragma unroll
        for (int j = 0; j < FN; j++) bv[j] = *(const bf16x8*)&Bs[wc * WN + j * 16 + lr][kp];
#pragma unroll
        for (int i = 0; i < FM; i++)
#pragma unroll
            for (int j = 0; j < FN; j++)
                acc[i][j] = __builtin_amdgcn_mfma_f32_16x16x32_bf16(av[i], bv[j], acc[i][j], 0, 0, 0);
        __syncthreads();
    }

    int dr = (l >> 4) * 4, dc = l & 15;
#pragma unroll
    for (int i = 0; i < FM; i++)
#pragma unroll
        for (int j = 0; j < FN; j++)
#pragma unroll
            for (int t = 0; t < 4; t++) {
                int row = bm + wr * WM + i * 16 + dr + t;
                int col = bn + wc * WN + j * 16 + dc;
                float v = acc[i][j][t];
                size_t off = zC + (size_t)row * ldc + col;
                if constexpr (EPI == 0)      ((__bf16*)Cout)[off] = (__bf16)(v + bias[col]);
                else if constexpr (EPI == 1) ((float*)Cout)[off]  = v + bias[col];
                else                         ((float*)Cout)[off]  = v * alpha;
            }
}

// ---------- fused attention: logits -> softmax -> probs(out) + PV ----------
// grid (32 q-tiles, 32 z=b*16+h), block 256 (4 waves).
// wave w owns score cols [w*256, w*256+256); acc[2 row-tiles][16 col-tiles].
__global__ __launch_bounds__(256) void attn_fused(
    const __bf16* __restrict__ PROJ, const __bf16* __restrict__ Vt,
    const float* __restrict__ mask, const float* __restrict__ CM,
    const float* __restrict__ TW, float* __restrict__ probs,
    __bf16* __restrict__ CTXb)
{
    __shared__ __bf16 Ps[32][1024];          // 64 KB, XOR-swizzled
    __shared__ float  red[32][4];            // cross-wave reduce
    __shared__ float  ctxred[2][16][64];     // 8 KB PV partials

    int tid = threadIdx.x;
    int w = tid >> 6, l = tid & 63;
    int lr = l & 15, kp = (l >> 4) * 8;
    int dr = (l >> 4) * 4, dc = l & 15;
    int bm = blockIdx.x * 32;
    int z = blockIdx.y, b = z >> 4, h = z & 15;

    const __bf16* Qg = PROJ + (size_t)(b * 1024 + bm) * LDP + h * 64;
    const __bf16* Kg = PROJ + (size_t)(b * 1024) * LDP + 1024 + h * 64;

    // ---- phase 1: QK^T, direct-global fragments ----
    bf16x8 av[2][2];
#pragma unroll
    for (int i = 0; i < 2; i++)
#pragma unroll
        for (int kk = 0; kk < 2; kk++)
            av[i][kk] = *(const bf16x8*)(Qg + (size_t)(i * 16 + lr) * LDP + kk * 32 + kp);

    f32x4 acc[2][16];
#pragma unroll
    for (int i = 0; i < 2; i++)
#pragma unroll
        for (int j = 0; j < 16; j++) acc[i][j] = (f32x4){0.f, 0.f, 0.f, 0.f};

#pragma unroll
    for (int j = 0; j < 16; j++) {
        const __bf16* Kt = Kg + (size_t)(w * 256 + j * 16 + lr) * LDP;
        bf16x8 b0 = *(const bf16x8*)(Kt + kp);
        bf16x8 b1 = *(const bf16x8*)(Kt + 32 + kp);
#pragma unroll
        for (int i = 0; i < 2; i++) {
            acc[i][j] = __builtin_amdgcn_mfma_f32_16x16x32_bf16(av[i][0], b0, acc[i][j], 0, 0, 0);
            acc[i][j] = __builtin_amdgcn_mfma_f32_16x16x32_bf16(av[i][1], b1, acc[i][j], 0, 0, 0);
        }
    }

    // ---- phase 2: epilogue + softmax ----
    float twv = TW[z];
    const float* Mb  = mask + (size_t)b * Sq * Sq;
    const float* CMb = CM   + (size_t)b * Sq * Sq;

    float pm[2][4];
#pragma unroll
    for (int i = 0; i < 2; i++)
#pragma unroll
        for (int t = 0; t < 4; t++) pm[i][t] = -1e30f;

#pragma unroll
    for (int i = 0; i < 2; i++)
#pragma unroll
        for (int t = 0; t < 4; t++) {
            size_t rb = (size_t)(bm + i * 16 + dr + t) * 1024;
#pragma unroll
            for (int j = 0; j < 16; j++) {
                int col = w * 256 + j * 16 + dc;
                float lv = (acc[i][j][t] * 0.125f + Mb[rb + col]) * twv + CMb[rb + col];
                acc[i][j][t] = lv;
                pm[i][t] = fmaxf(pm[i][t], lv);
            }
        }
#pragma unroll
    for (int i = 0; i < 2; i++)
#pragma unroll
        for (int t = 0; t < 4; t++) {
#pragma unroll
            for (int off = 1; off < 16; off <<= 1) pm[i][t] = fmaxf(pm[i][t], __shfl_xor(pm[i][t], off));
        }
    if (dc == 0)
#pragma unroll
        for (int i = 0; i < 2; i++)
#pragma unroll
            for (int t = 0; t < 4; t++) red[i * 16 + dr + t][w] = pm[i][t];
    __syncthreads();
    float m8[2][4];
#pragma unroll
    for (int i = 0; i < 2; i++)
#pragma unroll
        for (int t = 0; t < 4; t++) {
            int r = i * 16 + dr + t;
            m8[i][t] = fmaxf(fmaxf(red[r][0], red[r][1]), fmaxf(red[r][2], red[r][3]));
        }

    float ps[2][4] = {};
#pragma unroll
    for (int i = 0; i < 2; i++)
#pragma unroll
        for (int t = 0; t < 4; t++) {
#pragma unroll
            for (int j = 0; j < 16; j++) {
                float e = __expf(acc[i][j][t] - m8[i][t]);
                acc[i][j][t] = e;
                ps[i][t] += e;
            }
#pragma unroll
            for (int off = 1; off < 16; off <<= 1) ps[i][t] += __shfl_xor(ps[i][t], off);
        }
    __syncthreads();                 // all max-reads done before reusing red
    if (dc == 0)
#pragma unroll
        for (int i = 0; i < 2; i++)
#pragma unroll
            for (int t = 0; t < 4; t++) red[i * 16 + dr + t][w] = ps[i][t];
    __syncthreads();

    float inv[2][4];
#pragma unroll
    for (int i = 0; i < 2; i++)
#pragma unroll
        for (int t = 0; t < 4; t++) {
            int r = i * 16 + dr + t;
            inv[i][t] = 1.0f / (red[r][0] + red[r][1] + red[r][2] + red[r][3]);
        }

    // ---- write probs (fp32, d_out) + P (bf16, swizzled LDS) ----
    float* Pg = probs + (size_t)z * Sq * Sq;
#pragma unroll
    for (int i = 0; i < 2; i++)
#pragma unroll
        for (int t = 0; t < 4; t++) {
            int row = i * 16 + dr + t;
            size_t rb = (size_t)(bm + row) * 1024;
#pragma unroll
            for (int j = 0; j < 16; j++) {
                int col = w * 256 + j * 16 + dc;
                float p = acc[i][j][t] * inv[i][t];
                Pg[rb + col] = p;
                *(__bf16*)((char*)&Ps[0][0] + ((row * 2048 + col * 2) ^ ((row & 7) << 4))) = (__bf16)p;
            }
        }
    __syncthreads();

    // ---- phase 3: PV.  wave w: row-tile i3 = w&1, k-half kh = w>>1 ----
    int i3 = w & 1, kh = w >> 1;
    const __bf16* Vg = Vt + ((size_t)b * 1024 + h * 64) * 1024;
    f32x4 c2[4];
#pragma unroll
    for (int nt = 0; nt < 4; nt++) c2[nt] = (f32x4){0.f, 0.f, 0.f, 0.f};

    int arow = i3 * 16 + lr;
#pragma unroll
    for (int s = 0; s < 16; s++) {
        int k0 = kh * 512 + s * 32 + kp;
        bf16x8 a = *(const bf16x8*)((char*)&Ps[0][0] + ((arow * 2048 + k0 * 2) ^ ((arow & 7) << 4)));
#pragma unroll
        for (int nt = 0; nt < 4; nt++) {
            bf16x8 bv = *(const bf16x8*)(Vg + (size_t)(nt * 16 + lr) * 1024 + k0);
            c2[nt] = __builtin_amdgcn_mfma_f32_16x16x32_bf16(a, bv, c2[nt], 0, 0, 0);
        }
    }
    if (kh)
#pragma unroll
        for (int nt = 0; nt < 4; nt++)
#pragma unroll
            for (int t = 0; t < 4; t++) ctxred[i3][dr + t][nt * 16 + dc] = c2[nt][t];
    __syncthreads();
    if (!kh) {
#pragma unroll
        for (int nt = 0; nt < 4; nt++)
#pragma unroll
            for (int t = 0; t < 4; t++) {
                float v = c2[nt][t] + ctxred[i3][dr + t][nt * 16 + dc];
                CTXb[(size_t)(b * 1024 + bm + i3 * 16 + dr + t) * 1024 + h * 64 + nt * 16 + dc] = (__bf16)v;
            }
    }
}

// ---------- prep kernels ----------
__global__ __launch_bounds__(256) void convert_f32_bf16(
    const float* __restrict__ src, __bf16* __restrict__ dst)
{
    int i = blockIdx.x * 256 + threadIdx.x;
    size_t base = (size_t)i * 8;
    float4 a = *(const float4*)(src + base);
    float4 b = *(const float4*)(src + base + 4);
    bf16x8 o;
    o[0] = (__bf16)a.x; o[1] = (__bf16)a.y; o[2] = (__bf16)a.z; o[3] = (__bf16)a.w;
    o[4] = (__bf16)b.x; o[5] = (__bf16)b.y; o[6] = (__bf16)b.z; o[7] = (__bf16)b.w;
    *(bf16x8*)(dst + base) = o;
}

// src[K][N] f32 -> dst[N][K] bf16
__global__ __launch_bounds__(256) void transpose_f32_bf16(
    const float* __restrict__ src, __bf16* __restrict__ dst, int K, int N)
{
    __shared__ float t[32][33];
    int tx = threadIdx.x, ty = threadIdx.y;
    int n0 = blockIdx.x * 32, k0 = blockIdx.y * 32;
#pragma unroll
    for (int i = 0; i < 4; i++)
        t[ty + i * 8][tx] = src[(size_t)(k0 + ty + i * 8) * N + n0 + tx];
    __syncthreads();
#pragma unroll
    for (int i = 0; i < 4; i++)
        dst[(size_t)(n0 + ty + i * 8) * K + k0 + tx] = (__bf16)t[tx][ty + i * 8];
}

// PROJ V-columns -> Vt[b][d][s]
__global__ __launch_bounds__(256) void transpose_v(
    const __bf16* __restrict__ PROJ, __bf16* __restrict__ Vt)
{
    int b = blockIdx.z;
    __shared__ __bf16 t[32][33];
    int tx = threadIdx.x, ty = threadIdx.y;
    int s0 = blockIdx.x * 32, d0 = blockIdx.y * 32;
#pragma unroll
    for (int i = 0; i < 4; i++)
        t[ty + i * 8][tx] = PROJ[(size_t)(b * 1024 + s0 + ty + i * 8) * LDP + 2048 + d0 + tx];
    __syncthreads();
#pragma unroll
    for (int i = 0; i < 4; i++)
        Vt[(size_t)(b * 1024 + d0 + ty + i * 8) * 1024 + s0 + tx] = t[tx][ty + i * 8];
}

__global__ void pack_bias(const float* bq, const float* bk, const float* bv,
                          const float* bcq, const float* bck, float* ball)
{
    int i = blockIdx.x * 256 + threadIdx.x;
    if (i >= LDP) return;
    float v;
    if (i < 1024) v = bq[i];
    else if (i < 2048) v = bk[i - 1024];
    else if (i < 3072) v = bv[i - 2048];
    else if (i < 5120) v = bcq[i - 3072];
    else v = bck[i - 5120];
    ball[i] = v;
}

__global__ void tw_kernel(const float* __restrict__ trust, const float* __restrict__ Wt,
                          const float* __restrict__ bt, float* __restrict__ tw)
{
    int i = threadIdx.x;
    if (i >= 32) return;
    int b = i >> 4, h = i & 15;
    float s = bt[h];
    for (int k = 0; k < 64; k++) s += trust[b * 64 + k] * Wt[k * 16 + h];
    tw[i] = s;
}

extern "C" void kernel_launch(void* const* d_in, const int* in_sizes, int n_in,
                              void* d_out, int out_size, void* d_ws, size_t ws_size,
                              hipStream_t stream)
{
    (void)in_sizes; (void)n_in; (void)out_size; (void)ws_size;
    const float* x     = (const float*)d_in[0];
    const float* mask  = (const float*)d_in[1];
    const float* trust = (const float*)d_in[2];
    const float* Wq  = (const float*)d_in[3];  const float* bq  = (const float*)d_in[4];
    const float* Wk  = (const float*)d_in[5];  const float* bk  = (const float*)d_in[6];
    const float* Wv  = (const float*)d_in[7];  const float* bv  = (const float*)d_in[8];
    const float* Wcq = (const float*)d_in[9];  const float* bcq = (const float*)d_in[10];
    const float* Wck = (const float*)d_in[11]; const float* bck = (const float*)d_in[12];
    const float* Wt  = (const float*)d_in[15]; const float* bt  = (const float*)d_in[16];
    const float* Wo  = (const float*)d_in[17]; const float* bo  = (const float*)d_in[18];

    float* out   = (float*)d_out;
    float* probs = out + (size_t)2 * Sq * 1024;

    constexpr size_t MB = 1u << 20;
    char* w8 = (char*)d_ws;
    __bf16* xb   = (__bf16*)(w8 + 0 * MB);    // 4 MB
    __bf16* Wall = (__bf16*)(w8 + 4 * MB);    // 14 MB  [7168][1024]
    float*  ball = (float*) (w8 + 19 * MB);   // 28 KB
    float*  TW   = (float*) (w8 + 19 * MB + 65536);
    __bf16* WoT  = (__bf16*)(w8 + 19 * MB + 131072);  // 2 MB (within 19..20 window? no -> put after)
    __bf16* PROJ = (__bf16*)(w8 + 22 * MB);   // 28 MB  [2048][7168]
    __bf16* Vt   = (__bf16*)(w8 + 50 * MB);   // 4 MB
    float*  CM   = (float*) (w8 + 54 * MB);   // 8 MB
    __bf16* CTXb = (__bf16*)(w8 + 62 * MB);   // 4 MB -> ends at 66... keep within: move
    // NOTE: relayout to stay under 64 MB high-water used in round 1:
    WoT  = (__bf16*)(w8 + 19 * MB + 131072);          // 19.125..21.125 MB
    PROJ = (__bf16*)(w8 + 22 * MB);                   // 22..50 MB
    Vt   = (__bf16*)(w8 + 50 * MB);                   // 50..54 MB
    CM   = (float*) (w8 + 54 * MB);                   // 54..62 MB
    CTXb = (__bf16*)(w8 + 4 * MB);                    // reuse Wall region? NO - Wall needed. ->
    CTXb = (__bf16*)(w8 + 0 * MB);                    // reuse xb: xb last used by proj GEMM, CTXb written after. 0..4 MB

    dim3 tb(32, 8);

    // prep
    convert_f32_bf16<<<1024, 256, 0, stream>>>(x, xb);
    transpose_f32_bf16<<<dim3(32, 32), tb, 0, stream>>>(Wq,  Wall + (size_t)0 * 1024 * 1024, 1024, 1024);
    transpose_f32_bf16<<<dim3(32, 32), tb, 0, stream>>>(Wk,  Wall + (size_t)1 * 1024 * 1024, 1024, 1024);
    transpose_f32_bf16<<<dim3(32, 32), tb, 0, stream>>>(Wv,  Wall + (size_t)2 * 1024 * 1024, 1024, 1024);
    transpose_f32_bf16<<<dim3(64, 32), tb, 0, stream>>>(Wcq, Wall + (size_t)3 * 1024 * 1024, 1024, 2048);
    transpose_f32_bf16<<<dim3(64, 32), tb, 0, stream>>>(Wck, Wall + (size_t)5 * 1024 * 1024, 1024, 2048);
    transpose_f32_bf16<<<dim3(32, 32), tb, 0, stream>>>(Wo,  WoT, 1024, 1024);
    pack_bias<<<28, 256, 0, stream>>>(bq, bk, bv, bcq, bck, ball);
    tw_kernel<<<1, 64, 0, stream>>>(trust, Wt, bt, TW);

    // packed projections: PROJ[2048][7168] = xb @ Wall^T + ball
    gemm_nt<128, 128, 0><<<dim3(16, 56, 1), 256, 0, stream>>>(
        xb, 1024, Wall, 1024, PROJ, LDP, ball, 1024, 0.f);

    // Vt[b][d][s]
    transpose_v<<<dim3(32, 32, 2), tb, 0, stream>>>(PROJ, Vt);

    // cmean = CQ @ CK^T * (0.125/32)
    gemm_nt<128, 64, 2><<<dim3(8, 16, 2), 256, 0, stream>>>(
        PROJ + 3072, LDP, PROJ + 5120, LDP, CM, 1024, nullptr, 2048, 0.00390625f);

    // fused attention: logits -> softmax -> probs + ctx
    attn_fused<<<dim3(32, 32), 256, 0, stream>>>(PROJ, Vt, mask, CM, TW, probs, CTXb);

    // output projection
    gemm_nt<128, 128, 1><<<dim3(16, 8, 1), 256, 0, stream>>>(
        CTXb, 1024, WoT, 1024, out, 1024, bo, 1024, 0.f);
}